// Round 1
// baseline (48827.585 us; speedup 1.0000x reference)
//
#include <hip/hip_runtime.h>
#include <stdint.h>

#define TSEQ 1024
#define H 256
#define H3 768
#define NV 50000
#define NBLK 256
#define NTHR 512
#define RPB 197          // w_out rows per block (blocks 1..255)
#define SOS_TOK 2

// ---- workspace layout (bytes) ----
#define WS_CTR    0        // int
#define WS_EPOCH  64       // int
#define WS_LSE    128      // float
#define WS_ABORT  192      // int
#define WS_H      4096     // float[256]
#define WS_GHE    8192     // float[2][768]
#define WS_GHD    16384    // float[2][768]
#define WS_PART   24576    // float4[256]
#define WS_GIENC  32768    // float[1024*768]
#define WS_TABLE  (32768 + 1024*768*4)
#define TABLE_BYTES ((size_t)NV * H3 * 4)

__device__ __forceinline__ int wait_ge(int* p, int target, int* abortf) {
  long cnt = 0;
  while (__hip_atomic_load(p, __ATOMIC_ACQUIRE, __HIP_MEMORY_SCOPE_AGENT) < target) {
    if (__hip_atomic_load(abortf, __ATOMIC_RELAXED, __HIP_MEMORY_SCOPE_AGENT) != 0) return 1;
    if (++cnt > 20000000L) {
      __hip_atomic_store(abortf, 1, __ATOMIC_RELAXED, __HIP_MEMORY_SCOPE_AGENT);
      return 1;
    }
    __builtin_amdgcn_s_sleep(2);
  }
  return 0;
}
__device__ __forceinline__ void publish(int* p, int v) {
  __threadfence();
  __hip_atomic_store(p, v, __ATOMIC_RELEASE, __HIP_MEMORY_SCOPE_AGENT);
}
__device__ __forceinline__ float sigmf(float x) { return 1.0f / (1.0f + expf(-x)); }

// ---- init: reset all control state every call (graph-replay safe) ----
extern "C" __global__ void k_init(char* ws) {
  int tid = threadIdx.x;
  if (tid == 0) {
    *(int*)(ws + WS_CTR) = 0;
    *(int*)(ws + WS_EPOCH) = 1;   // h_0 (zeros) is "published"
    *(float*)(ws + WS_LSE) = 0.f;
    *(int*)(ws + WS_ABORT) = 0;
  }
  if (tid < H) ((float*)(ws + WS_H))[tid] = 0.f;
}

// ---- encoder input-transform precompute: gi_enc[t][r] = b_ih[r] + w_ih[r,:] @ enc_emb[x[t]] ----
extern "C" __global__ void k_enc_gi(const int* __restrict__ x, const float* __restrict__ emb,
                                    const float* __restrict__ wih, const float* __restrict__ bih,
                                    float* __restrict__ gi) {
  int t = blockIdx.x, tid = threadIdx.x;
  __shared__ float4 se4[H / 4];
  float* se = (float*)se4;
  int tok = x[t];
  if (tid < H) se[tid] = emb[(size_t)tok * H + tid];
  __syncthreads();
  for (int q = 0; q < 3; q++) {
    int r = q * H + tid;
    const float4* w4 = (const float4*)(wih + (size_t)r * H);
    float a = bih[r];
    for (int k = 0; k < H / 4; k++) {
      float4 wv = w4[k], ev = se4[k];
      a += wv.x * ev.x + wv.y * ev.y + wv.z * ev.z + wv.w * ev.w;
    }
    gi[(size_t)t * H3 + r] = a;
  }
}

// ---- decoder gi table: table[v][r] = b_ih[r] + w_ih[r,:] @ relu(dec_emb[v]) ----
extern "C" __global__ void k_table(const float* __restrict__ emb, const float* __restrict__ wih,
                                   const float* __restrict__ bih, float* __restrict__ table) {
  int tid = threadIdx.x;
  int v0 = blockIdx.x * 16;
  __shared__ float4 se4[16][H / 4];
  float* se = (float*)se4;
  for (int idx = tid; idx < 16 * H; idx += 256) {
    int j = idx >> 8, k = idx & 255;
    se[j * H + k] = fmaxf(emb[(size_t)(v0 + j) * H + k], 0.f);
  }
  __syncthreads();
  for (int q = 0; q < 3; q++) {
    int r = q * H + tid;
    const float4* w4 = (const float4*)(wih + (size_t)r * H);
    float bb = bih[r];
    float a[16];
#pragma unroll
    for (int j = 0; j < 16; j++) a[j] = bb;
    for (int k = 0; k < H / 4; k++) {
      float4 wv = w4[k];
#pragma unroll
      for (int j = 0; j < 16; j++) {
        float4 ev = se4[j][k];
        a[j] += wv.x * ev.x + wv.y * ev.y + wv.z * ev.z + wv.w * ev.w;
      }
    }
#pragma unroll
    for (int j = 0; j < 16; j++) table[(size_t)(v0 + j) * H3 + r] = a[j];
  }
}

// ---- persistent main kernel: encoder scan + decoder greedy loop ----
extern "C" __global__ void __launch_bounds__(NTHR, 2)
k_main(const float* __restrict__ enc_whh, const float* __restrict__ enc_bhh,
       const float* __restrict__ dec_emb, const float* __restrict__ dec_wih,
       const float* __restrict__ dec_whh, const float* __restrict__ dec_bih,
       const float* __restrict__ dec_bhh, const float* __restrict__ w_out,
       const float* __restrict__ b_out, float* __restrict__ out,
       char* __restrict__ ws, int use_table) {
  const int b = blockIdx.x, tid = threadIdx.x;
  int* ctr = (int*)(ws + WS_CTR);
  int* epoch = (int*)(ws + WS_EPOCH);
  float* lse_slot = (float*)(ws + WS_LSE);
  int* abortf = (int*)(ws + WS_ABORT);
  float* hbuf = (float*)(ws + WS_H);
  float* ghE = (float*)(ws + WS_GHE);
  float* ghD = (float*)(ws + WS_GHD);
  float4* part = (float4*)(ws + WS_PART);
  const float* gi_enc = (const float*)(ws + WS_GIENC);
  const float* table = (const float*)(ws + WS_TABLE);

  __shared__ float4 sh_h4[H / 4];
  float* sh_h = (float*)sh_h4;
  __shared__ float sh_we[3][H];
  __shared__ float sh_wd[3][H];
  __shared__ float sh_logit[RPB];
  __shared__ float sh_rv[8];
  __shared__ int sh_ri[8];
  __shared__ float sh_bc[2];
  __shared__ int sh_tok;
  __shared__ float sh_lse;
  __shared__ int sh_abort;
  __shared__ float4 sh_e4[H / 4];
  float* sh_e = (float*)sh_e4;
  __shared__ float sh_gi[H3];
  __shared__ float pad[11264];           // LDS pad: caps CU packing at <=2 blocks
  if (use_table == 2) pad[tid] = 0.f;    // unreachable at runtime; keeps pad allocated

  // ---- prologue: stage per-block GRU rows; load w_out fragment into registers ----
  for (int k = tid; k < 3 * H; k += NTHR) {
    int q = k >> 8, c = k & 255;
    sh_we[q][c] = enc_whh[(size_t)(3 * b + q) * H + c];
    sh_wd[q][c] = dec_whh[(size_t)(3 * b + q) * H + c];
  }
  const int rowbase = (b - 1) * RPB;
  const int nrows = (b >= 1) ? min(RPB, max(0, NV - rowbase)) : 0;
  const int p = tid >> 1, hf = tid & 1;
  const bool wact = (b >= 1) && (p < nrows);
  float4 wreg[32];
  if (wact) {
    const float4* wp = (const float4*)(w_out + (size_t)(rowbase + p) * H + hf * 128);
#pragma unroll
    for (int i = 0; i < 32; ++i) wreg[i] = wp[i];
  } else {
#pragma unroll
    for (int i = 0; i < 32; ++i) wreg[i] = make_float4(0.f, 0.f, 0.f, 0.f);
  }
  if (b == 0) {
    for (int j = tid; j < H; j += NTHR) sh_h[j] = 0.f;
    if (tid == 0) sh_tok = SOS_TOK;
  }
  __syncthreads();

  // 3-row matvec helper: rows 3b..3b+2 of (w @ sh_h) + bias -> dst
  auto row3 = [&](const float(&wr)[3][H], const float* bias, float* dst) {
    int q = tid >> 7, i = tid & 127;
    float pp = 0.f;
    if (q < 3) pp = wr[q][2 * i] * sh_h[2 * i] + wr[q][2 * i + 1] * sh_h[2 * i + 1];
#pragma unroll
    for (int off = 32; off >= 1; off >>= 1) pp += __shfl_xor(pp, off);
    int w = tid >> 6;
    if (q < 3 && (tid & 63) == 0) sh_rv[w] = pp;
    __syncthreads();
    if (tid < 3) dst[3 * b + tid] = sh_rv[2 * tid] + sh_rv[2 * tid + 1] + bias[3 * b + tid];
    __syncthreads();
  };
  // elementwise GRU update (threads 0..255); writes hbuf and sh_h
  auto gru_update = [&](const float* gi_src, const float* gh_src) {
    if (tid < H) {
      float gir = gi_src[tid], giz = gi_src[H + tid], gin = gi_src[2 * H + tid];
      float ghr = gh_src[tid], ghz = gh_src[H + tid], ghn = gh_src[2 * H + tid];
      float r = sigmf(gir + ghr), z = sigmf(giz + ghz);
      float n = tanhf(gin + r * ghn);
      float hn = (1.f - z) * n + z * hbuf[tid];
      hbuf[tid] = hn;
      sh_h[tid] = hn;
    }
  };
#define BLOCK_WAIT(P, TGT)                           \
  {                                                  \
    if (tid == 0) sh_abort = wait_ge(P, TGT, abortf);\
    __syncthreads();                                 \
    if (sh_abort) return;                            \
  }

  // ===================== ENCODER =====================
  for (int t = 0; t < TSEQ; ++t) {
    float* ghp = ghE + (t & 1) * H3;
    if (b == 0) {
      row3(sh_we, enc_bhh, ghp);
      if (tid == 0) { __threadfence(); atomicAdd(ctr, 1); }
      BLOCK_WAIT(ctr, NBLK * (t + 1));
      gru_update(gi_enc + (size_t)t * H3, ghp);
      __syncthreads();
      if (tid == 0) publish(epoch, t + 2);
    } else {
      BLOCK_WAIT(epoch, t + 1);
      for (int j = tid; j < H; j += NTHR) sh_h[j] = hbuf[j];
      __syncthreads();
      row3(sh_we, enc_bhh, ghp);
      if (tid == 0) { __threadfence(); atomicAdd(ctr, 1); }
    }
  }
  // ===================== BRIDGE: dec-gh(h_enc) -> ghD[0] =====================
  if (b == 0) {
    row3(sh_wd, dec_bhh, ghD);
    if (tid == 0) { __threadfence(); atomicAdd(ctr, 1); }
    BLOCK_WAIT(ctr, NBLK * (TSEQ + 1));
  } else {
    BLOCK_WAIT(epoch, TSEQ + 1);
    for (int j = tid; j < H; j += NTHR) sh_h[j] = hbuf[j];
    __syncthreads();
    row3(sh_wd, dec_bhh, ghD);
    if (tid == 0) { __threadfence(); atomicAdd(ctr, 1); }
  }
  // ===================== DECODER =====================
  float lse_prev = 0.f;
  for (int t = 0; t < TSEQ; ++t) {
    if (b == 0) {
      const float* ghp = ghD + (t & 1) * H3;
      if (use_table) {
        gru_update(table + (size_t)sh_tok * H3, ghp);
      } else {
        int tk = sh_tok;
        for (int j = tid; j < H; j += NTHR) sh_e[j] = fmaxf(dec_emb[(size_t)tk * H + j], 0.f);
        __syncthreads();
        {
          int r = tid;
          const float4* w4 = (const float4*)(dec_wih + (size_t)r * H);
          float a = dec_bih[r];
          for (int k = 0; k < H / 4; k++) {
            float4 wv = w4[k], ev = sh_e4[k];
            a += wv.x * ev.x + wv.y * ev.y + wv.z * ev.z + wv.w * ev.w;
          }
          sh_gi[r] = a;
        }
        if (tid < H3 - NTHR) {
          int r = NTHR + tid;
          const float4* w4 = (const float4*)(dec_wih + (size_t)r * H);
          float a = dec_bih[r];
          for (int k = 0; k < H / 4; k++) {
            float4 wv = w4[k], ev = sh_e4[k];
            a += wv.x * ev.x + wv.y * ev.y + wv.z * ev.z + wv.w * ev.w;
          }
          sh_gi[r] = a;
        }
        __syncthreads();
        gru_update(sh_gi, ghp);
      }
      __syncthreads();
      if (tid == 0) {
        lse_slot[0] = lse_prev;
        publish(epoch, TSEQ + 2 + t);
      }
      row3(sh_wd, dec_bhh, ghD + ((t + 1) & 1) * H3);
      if (tid == 0) { __threadfence(); atomicAdd(ctr, 1); }
      BLOCK_WAIT(ctr, NBLK * (TSEQ + 2 + t));
      // merge partials -> token_{t+1}, lse_t
      float4 pa = make_float4(0.f, 0.f, 0.f, 0.f);
      bool valid = (tid >= 1 && tid < NBLK);
      float mv = -INFINITY;
      int mi = 0x7fffffff;
      if (valid) { pa = part[tid]; mv = pa.x; mi = __float_as_int(pa.z); }
#pragma unroll
      for (int off = 32; off >= 1; off >>= 1) {
        float ov = __shfl_xor(mv, off);
        int oi = __shfl_xor(mi, off);
        if (ov > mv || (ov == mv && oi < mi)) { mv = ov; mi = oi; }
      }
      int w = tid >> 6;
      if ((tid & 63) == 0) { sh_rv[w] = mv; sh_ri[w] = mi; }
      __syncthreads();
      if (tid == 0) {
        float bm = sh_rv[0];
        int bi = sh_ri[0];
        for (int k = 1; k < 8; k++)
          if (sh_rv[k] > bm || (sh_rv[k] == bm && sh_ri[k] < bi)) { bm = sh_rv[k]; bi = sh_ri[k]; }
        sh_bc[0] = bm;
        sh_tok = bi;
      }
      __syncthreads();
      float gmax = sh_bc[0];
      float c = valid ? pa.y * expf(pa.x - gmax) : 0.f;
#pragma unroll
      for (int off = 32; off >= 1; off >>= 1) c += __shfl_xor(c, off);
      if ((tid & 63) == 0) sh_rv[w] = c;
      __syncthreads();
      if (tid == 0) {
        float s = 0.f;
        for (int k = 0; k < 8; k++) s += sh_rv[k];
        lse_prev = gmax + logf(s);
      }
      __syncthreads();
    } else {
      BLOCK_WAIT(epoch, TSEQ + 2 + t);
      for (int j = tid; j < H; j += NTHR) sh_h[j] = hbuf[j];
      if (tid == 0) sh_lse = lse_slot[0];
      __syncthreads();
      if (t > 0 && tid < nrows)
        out[(size_t)(t - 1) * NV + rowbase + tid] = sh_logit[tid] - sh_lse;
      row3(sh_wd, dec_bhh, ghD + ((t + 1) & 1) * H3);
      // logits from register-resident w_out
      float acc = 0.f;
      if (wact) {
        const float4* h4 = ((const float4*)sh_h) + hf * 32;
#pragma unroll
        for (int i = 0; i < 32; ++i) {
          float4 wv = wreg[i], hv = h4[i];
          acc += wv.x * hv.x + wv.y * hv.y + wv.z * hv.z + wv.w * hv.w;
        }
      }
      acc += __shfl_xor(acc, 1);
      if (wact && hf == 0) sh_logit[p] = acc + b_out[rowbase + p];
      __syncthreads();
      float lv = (tid < nrows) ? sh_logit[tid] : -INFINITY;
      int li = (tid < nrows) ? (rowbase + tid) : 0x7fffffff;
      float mv = lv;
      int mi = li;
#pragma unroll
      for (int off = 32; off >= 1; off >>= 1) {
        float ov = __shfl_xor(mv, off);
        int oi = __shfl_xor(mi, off);
        if (ov > mv || (ov == mv && oi < mi)) { mv = ov; mi = oi; }
      }
      int w = tid >> 6;
      if ((tid & 63) == 0) { sh_rv[w] = mv; sh_ri[w] = mi; }
      __syncthreads();
      if (tid == 0) {
        float bm = sh_rv[0];
        int bi = sh_ri[0];
        for (int k = 1; k < 8; k++)
          if (sh_rv[k] > bm || (sh_rv[k] == bm && sh_ri[k] < bi)) { bm = sh_rv[k]; bi = sh_ri[k]; }
        sh_bc[0] = bm;
        sh_ri[0] = bi;
      }
      __syncthreads();
      float bm = sh_bc[0];
      float ec = (tid < nrows) ? expf(sh_logit[tid] - bm) : 0.f;
#pragma unroll
      for (int off = 32; off >= 1; off >>= 1) ec += __shfl_xor(ec, off);
      if ((tid & 63) == 0) sh_rv[w] = ec;
      __syncthreads();
      if (tid == 0) {
        float s = 0.f;
        for (int k = 0; k < 8; k++) s += sh_rv[k];
        part[b] = make_float4(bm, s, __int_as_float(sh_ri[0]), 0.f);
        __threadfence();
        atomicAdd(ctr, 1);
      }
    }
  }
  // ===================== EPILOGUE: flush logp row 1023 =====================
  if (b == 0) {
    if (tid == 0) {
      lse_slot[0] = lse_prev;
      publish(epoch, 2 * TSEQ + 2);
    }
  } else {
    BLOCK_WAIT(epoch, 2 * TSEQ + 2);
    if (tid == 0) sh_lse = lse_slot[0];
    __syncthreads();
    if (tid < nrows)
      out[(size_t)(TSEQ - 1) * NV + rowbase + tid] = sh_logit[tid] - sh_lse;
  }
#undef BLOCK_WAIT
}

extern "C" void kernel_launch(void* const* d_in, const int* in_sizes, int n_in,
                              void* d_out, int out_size, void* d_ws, size_t ws_size,
                              hipStream_t stream) {
  (void)in_sizes; (void)n_in; (void)out_size;
  const int* x = (const int*)d_in[0];
  const float* enc_emb = (const float*)d_in[1];
  const float* enc_wih = (const float*)d_in[2];
  const float* enc_whh = (const float*)d_in[3];
  const float* enc_bih = (const float*)d_in[4];
  const float* enc_bhh = (const float*)d_in[5];
  const float* dec_emb = (const float*)d_in[6];
  const float* dec_wih = (const float*)d_in[7];
  const float* dec_whh = (const float*)d_in[8];
  const float* dec_bih = (const float*)d_in[9];
  const float* dec_bhh = (const float*)d_in[10];
  const float* w_out = (const float*)d_in[11];
  const float* b_out = (const float*)d_in[12];
  float* out = (float*)d_out;
  char* ws = (char*)d_ws;

  int use_table = (ws_size >= (size_t)WS_TABLE + TABLE_BYTES) ? 1 : 0;

  k_init<<<1, 256, 0, stream>>>(ws);
  k_enc_gi<<<TSEQ, 256, 0, stream>>>(x, enc_emb, enc_wih, enc_bih, (float*)(ws + WS_GIENC));
  if (use_table)
    k_table<<<NV / 16, 256, 0, stream>>>(dec_emb, dec_wih, dec_bih, (float*)(ws + WS_TABLE));
  k_main<<<NBLK, NTHR, 0, stream>>>(enc_whh, enc_bhh, dec_emb, dec_wih, dec_whh, dec_bih,
                                    dec_bhh, w_out, b_out, out, ws, use_table);
}

// Round 3
// 44842.444 us; speedup vs baseline: 1.0889x; 1.0889x over previous
//
#include <hip/hip_runtime.h>
#include <stdint.h>

#define TSEQ 1024
#define H 256
#define H3 768
#define NV 50000
#define NBLK 256
#define NTHR 512
#define RPB 196            // 256 * 196 = 50176 >= 50000
#define SOS_TOK 2
#define SWEEP_LIMIT 400000

// ---- workspace layout (bytes) ----
#define WS_PART   4096                       // float4[2][512]  (A,B per block, parity dbuf) 16KB
#define WS_STAMP  24576                      // int stamps, stride 16 dwords (64B), 256 entries
#define WS_GIENC  65536                      // float[1024*768] = 3MB
#define WS_TABLE  (65536 + TSEQ * H3 * 4)
#define TABLE_BYTES ((size_t)NV * H3 * 4)

#define ACQ_FENCE() __builtin_amdgcn_fence(__ATOMIC_ACQUIRE, "agent")

// ---- init: reset stamps every call (graph-replay safe) ----
extern "C" __global__ void k_init(char* ws) {
  int tid = threadIdx.x;
  if (tid < NBLK) ((int*)(ws + WS_STAMP))[tid * 16] = 0;
}

// ---- encoder input-transform: gi_enc[t][r] = b_ih[r] + w_ih[r,:] @ enc_emb[x[t]], 16 tokens/block ----
extern "C" __global__ void k_enc_gi(const int* __restrict__ x, const float* __restrict__ emb,
                                    const float* __restrict__ wih, const float* __restrict__ bih,
                                    float* __restrict__ gi) {
  int tid = threadIdx.x;
  int t0 = blockIdx.x * 16;
  __shared__ float4 se4[16][H / 4];
  float* se = (float*)se4;
  for (int idx = tid; idx < 16 * H; idx += 256) {
    int j = idx >> 8, k = idx & 255;
    se[j * H + k] = emb[(size_t)x[t0 + j] * H + k];
  }
  __syncthreads();
  for (int q = 0; q < 3; q++) {
    int r = q * H + tid;
    const float4* w4 = (const float4*)(wih + (size_t)r * H);
    float bb = bih[r];
    float a[16];
#pragma unroll
    for (int j = 0; j < 16; j++) a[j] = bb;
    for (int k = 0; k < H / 4; k++) {
      float4 wv = w4[k];
#pragma unroll
      for (int j = 0; j < 16; j++) {
        float4 ev = se4[j][k];
        a[j] += wv.x * ev.x + wv.y * ev.y + wv.z * ev.z + wv.w * ev.w;
      }
    }
#pragma unroll
    for (int j = 0; j < 16; j++) gi[(size_t)(t0 + j) * H3 + r] = a[j];
  }
}

// ---- decoder gi table: table[v][r] = b_ih[r] + w_ih[r,:] @ relu(dec_emb[v]) ----
extern "C" __global__ void k_table(const float* __restrict__ emb, const float* __restrict__ wih,
                                   const float* __restrict__ bih, float* __restrict__ table) {
  int tid = threadIdx.x;
  int v0 = blockIdx.x * 16;
  __shared__ float4 se4[16][H / 4];
  float* se = (float*)se4;
  for (int idx = tid; idx < 16 * H; idx += 256) {
    int j = idx >> 8, k = idx & 255;
    se[j * H + k] = fmaxf(emb[(size_t)(v0 + j) * H + k], 0.f);
  }
  __syncthreads();
  for (int q = 0; q < 3; q++) {
    int r = q * H + tid;
    const float4* w4 = (const float4*)(wih + (size_t)r * H);
    float bb = bih[r];
    float a[16];
#pragma unroll
    for (int j = 0; j < 16; j++) a[j] = bb;
    for (int k = 0; k < H / 4; k++) {
      float4 wv = w4[k];
#pragma unroll
      for (int j = 0; j < 16; j++) {
        float4 ev = se4[j][k];
        a[j] += wv.x * ev.x + wv.y * ev.y + wv.z * ev.z + wv.w * ev.w;
      }
    }
#pragma unroll
    for (int j = 0; j < 16; j++) table[(size_t)(v0 + j) * H3 + r] = a[j];
  }
}

// ---- persistent symmetric kernel: all 256 blocks are peers; one all-to-all exchange per step ----
extern "C" __global__ void __launch_bounds__(NTHR, 2)
k_main(const float* __restrict__ enc_whh, const float* __restrict__ enc_bhh,
       const float* __restrict__ dec_emb, const float* __restrict__ dec_wih,
       const float* __restrict__ dec_whh, const float* __restrict__ dec_bih,
       const float* __restrict__ dec_bhh, const float* __restrict__ w_out,
       const float* __restrict__ b_out, float* __restrict__ out,
       char* __restrict__ ws, int use_table) {
  const int b = blockIdx.x, tid = threadIdx.x;
  float4* part = (float4*)(ws + WS_PART);
  int* stampp = (int*)(ws + WS_STAMP);
  const float* gi_enc = (const float*)(ws + WS_GIENC);
  const float* table = (const float*)(ws + WS_TABLE);

  __shared__ float sh_h[H];
  __shared__ float sh_we[3][H];
  __shared__ float sh_wd[3][H];
  __shared__ float sh_wi[3][H];
  __shared__ float sh_gi[H3];
  __shared__ float gh_lds[H3];
  __shared__ float sh_logit[RPB];
  __shared__ float sh_bout[RPB];
  __shared__ float sh_gh3[3];
  __shared__ float sh_rv[8];
  __shared__ int sh_ri[8];
  __shared__ float sh_sv[8];
  __shared__ float sh_e[H];

  // ---- prologue staging ----
  for (int k = tid; k < 3 * H; k += NTHR) {
    int q = k >> 8, c = k & 255;
    sh_we[q][c] = enc_whh[(size_t)(3 * b + q) * H + c];
    sh_wd[q][c] = dec_whh[(size_t)(3 * b + q) * H + c];
    if (!use_table) sh_wi[q][c] = dec_wih[(size_t)(3 * b + q) * H + c];
  }
  const int rowbase = b * RPB;
  const int nrows = min(RPB, max(0, NV - rowbase));
  const int p = tid >> 1, hf = tid & 1;
  const bool wact = (p < nrows);
  float4 wreg[32];
  if (wact) {
    const float4* wp = (const float4*)(w_out + (size_t)(rowbase + p) * H + hf * 128);
#pragma unroll
    for (int i = 0; i < 32; ++i) wreg[i] = wp[i];
  } else {
#pragma unroll
    for (int i = 0; i < 32; ++i) wreg[i] = make_float4(0.f, 0.f, 0.f, 0.f);
  }
  if (tid < RPB) sh_bout[tid] = (tid < nrows) ? b_out[rowbase + tid] : 0.f;
  for (int j = tid; j < H; j += NTHR) sh_h[j] = 0.f;
  for (int j = tid; j < H3; j += NTHR) {
    gh_lds[j] = enc_bhh[j];   // w_hh @ 0 + b_hh
    sh_gi[j] = gi_enc[j];     // gi for t=0
  }
  __syncthreads();
  int e = 0;
  int tok = SOS_TOK;

  auto wave_maxidx = [&](float& mv, int& mi) {
#pragma unroll
    for (int off = 32; off >= 1; off >>= 1) {
      float ov = __shfl_xor(mv, off);
      int oi = __shfl_xor(mi, off);
      if (ov > mv || (ov == mv && oi < mi)) { mv = ov; mi = oi; }
    }
  };
  // rows 3b..3b+2 of (wr @ vin) + bias -> sh_gh3[0..2]
  auto row3 = [&](const float(&wr)[3][H], const float* bias, const float* vin) {
    int q = tid >> 7, i = tid & 127;
    float pp = 0.f;
    if (q < 3) pp = wr[q][2 * i] * vin[2 * i] + wr[q][2 * i + 1] * vin[2 * i + 1];
#pragma unroll
    for (int off = 32; off >= 1; off >>= 1) pp += __shfl_xor(pp, off);
    if (q < 3 && (tid & 63) == 0) sh_rv[tid >> 6] = pp;
    __syncthreads();
    if (tid < 3) sh_gh3[tid] = sh_rv[2 * tid] + sh_rv[2 * tid + 1] + bias[3 * b + tid];
    __syncthreads();
  };
  auto gru_step = [&]() {
    if (tid < H) {
      float gir = sh_gi[tid], giz = sh_gi[H + tid], gin = sh_gi[2 * H + tid];
      float ghr = gh_lds[tid], ghz = gh_lds[H + tid], ghn = gh_lds[2 * H + tid];
      float r = 1.f / (1.f + expf(-(gir + ghr)));
      float z = 1.f / (1.f + expf(-(giz + ghz)));
      float n = tanhf(gin + r * ghn);
      sh_h[tid] = (1.f - z) * n + z * sh_h[tid];
    }
    __syncthreads();
  };
  auto wait_all = [&](int est) -> bool {
    for (int sweep = 0;; ++sweep) {
      int ok = 1;
      if (tid < NBLK)
        ok = (__hip_atomic_load(stampp + tid * 16, __ATOMIC_RELAXED,
                                __HIP_MEMORY_SCOPE_AGENT) >= est);
      if (__syncthreads_and(ok)) break;
      if (sweep > SWEEP_LIMIT) return false;  // uniform: sweep identical across block
    }
    ACQ_FENCE();
    return true;
  };
  auto publishA = [&](float a3, float b0v, float b1v, int est) {
    if (tid == 0) {
      float4* pp_ = part + (size_t)(est & 1) * 512 + 2 * b;
      pp_[0] = make_float4(sh_gh3[0], sh_gh3[1], sh_gh3[2], a3);
      pp_[1] = make_float4(b0v, b1v, 0.f, 0.f);
      // release store orders the two data stores above (same thread) before the stamp
      __hip_atomic_store(stampp + b * 16, est, __ATOMIC_RELEASE, __HIP_MEMORY_SCOPE_AGENT);
    }
  };
  auto gather_gh = [&](float* dst, int est) {
    if (tid < NBLK) {
      float4 A = part[(size_t)(est & 1) * 512 + 2 * tid];
      dst[3 * tid] = A.x; dst[3 * tid + 1] = A.y; dst[3 * tid + 2] = A.z;
    }
  };

  // ===================== ENCODER =====================
  for (int t = 0; t < TSEQ; ++t) {
    gru_step();                       // h_t from gi_enc[t], gh(h_{t-1})
    if (t + 1 < TSEQ) {
      row3(sh_we, enc_bhh, sh_h);     // gh rows for t+1
      ++e;
      publishA(0.f, 0.f, 0.f, e);
      for (int j = tid; j < H3; j += NTHR)     // prefetch gi for t+1 during wait
        sh_gi[j] = gi_enc[(size_t)(t + 1) * H3 + j];
      if (!wait_all(e)) return;
      gather_gh(gh_lds, e);
      __syncthreads();
    }
  }
  // ===================== BRIDGE: exchange dec-gh(h_enc) =====================
  row3(sh_wd, dec_bhh, sh_h);
  ++e;
  publishA(0.f, 0.f, 0.f, e);
  if (!wait_all(e)) return;
  gather_gh(gh_lds, e);
  __syncthreads();

  // ===================== DECODER =====================
  for (int t = 0; t < TSEQ; ++t) {
    // gi = b_ih + w_ih @ relu(emb[tok])
    if (use_table) {
      for (int j = tid; j < H3; j += NTHR) sh_gi[j] = table[(size_t)tok * H3 + j];
    } else {
      for (int j = tid; j < H; j += NTHR) sh_e[j] = fmaxf(dec_emb[(size_t)tok * H + j], 0.f);
      __syncthreads();
      row3(sh_wi, dec_bih, sh_e);     // 3 gi rows
      ++e;
      publishA(0.f, 0.f, 0.f, e);
      if (!wait_all(e)) return;
      gather_gh(sh_gi, e);
    }
    __syncthreads();
    gru_step();                        // h_t (identical in all blocks)
    // logits from register-resident w_out
    float acc = 0.f;
    if (wact) {
      const float4* h4 = ((const float4*)sh_h) + hf * 32;
#pragma unroll
      for (int i = 0; i < 32; ++i) {
        float4 wv = wreg[i], hv = h4[i];
        acc += wv.x * hv.x + wv.y * hv.y + wv.z * hv.z + wv.w * hv.w;
      }
    }
    acc += __shfl_xor(acc, 1);
    if (wact && hf == 0) sh_logit[p] = acc + sh_bout[p];
    // gh rows for t+1 (barriers inside also publish sh_logit)
    row3(sh_wd, dec_bhh, sh_h);
    // block-local max/argmax over own rows
    float mv = (tid < nrows) ? sh_logit[tid] : -INFINITY;
    int mi = (tid < nrows) ? (rowbase + tid) : 0x7fffffff;
    wave_maxidx(mv, mi);
    if ((tid & 63) == 0) { sh_rv[tid >> 6] = mv; sh_ri[tid >> 6] = mi; }
    __syncthreads();
    float bmax = sh_rv[0]; int bidx = sh_ri[0];
#pragma unroll
    for (int k = 1; k < 8; ++k)
      if (sh_rv[k] > bmax || (sh_rv[k] == bmax && sh_ri[k] < bidx)) { bmax = sh_rv[k]; bidx = sh_ri[k]; }
    // block-local sum of exp
    float ec = (tid < nrows) ? expf(sh_logit[tid] - bmax) : 0.f;
#pragma unroll
    for (int off = 32; off >= 1; off >>= 1) ec += __shfl_xor(ec, off);
    if ((tid & 63) == 0) sh_sv[tid >> 6] = ec;
    __syncthreads();
    float bsum = 0.f;
#pragma unroll
    for (int k = 0; k < 8; ++k) bsum += sh_sv[k];
    // one exchange: {gh3, bmax} {bsum, bidx}
    ++e;
    publishA(bmax, bsum, __int_as_float(bidx), e);
    if (!wait_all(e)) return;
    float bm_e = -INFINITY, sv = 0.f; int ie = 0x7fffffff;
    if (tid < NBLK) {
      const float4* pp_ = part + (size_t)(e & 1) * 512 + 2 * tid;
      float4 A = pp_[0]; float4 Bv = pp_[1];
      gh_lds[3 * tid] = A.x; gh_lds[3 * tid + 1] = A.y; gh_lds[3 * tid + 2] = A.z;
      bm_e = A.w; sv = Bv.x; ie = __float_as_int(Bv.y);
    }
    // redundant identical merge -> gmax, token, lse (bitwise-identical in every block)
    float mv2 = bm_e; int mi2 = ie;
    wave_maxidx(mv2, mi2);
    if ((tid & 63) == 0) { sh_rv[tid >> 6] = mv2; sh_ri[tid >> 6] = mi2; }
    __syncthreads();
    float gmax = sh_rv[0]; int gidx = sh_ri[0];
#pragma unroll
    for (int k = 1; k < 8; ++k)
      if (sh_rv[k] > gmax || (sh_rv[k] == gmax && sh_ri[k] < gidx)) { gmax = sh_rv[k]; gidx = sh_ri[k]; }
    float c = (tid < NBLK) ? sv * expf(bm_e - gmax) : 0.f;
#pragma unroll
    for (int off = 32; off >= 1; off >>= 1) c += __shfl_xor(c, off);
    if ((tid & 63) == 0) sh_sv[tid >> 6] = c;
    __syncthreads();
    float S = 0.f;
#pragma unroll
    for (int k = 0; k < 8; ++k) S += sh_sv[k];
    float lse = gmax + logf(S);
    if (tid < nrows) out[(size_t)t * NV + rowbase + tid] = sh_logit[tid] - lse;
    tok = gidx;
  }
}

extern "C" void kernel_launch(void* const* d_in, const int* in_sizes, int n_in,
                              void* d_out, int out_size, void* d_ws, size_t ws_size,
                              hipStream_t stream) {
  (void)in_sizes; (void)n_in; (void)out_size;
  const int* x = (const int*)d_in[0];
  const float* enc_emb = (const float*)d_in[1];
  const float* enc_wih = (const float*)d_in[2];
  const float* enc_whh = (const float*)d_in[3];
  const float* enc_bih = (const float*)d_in[4];
  const float* enc_bhh = (const float*)d_in[5];
  const float* dec_emb = (const float*)d_in[6];
  const float* dec_wih = (const float*)d_in[7];
  const float* dec_whh = (const float*)d_in[8];
  const float* dec_bih = (const float*)d_in[9];
  const float* dec_bhh = (const float*)d_in[10];
  const float* w_out = (const float*)d_in[11];
  const float* b_out = (const float*)d_in[12];
  float* out = (float*)d_out;
  char* ws = (char*)d_ws;

  int use_table = (ws_size >= (size_t)WS_TABLE + TABLE_BYTES) ? 1 : 0;

  k_init<<<1, 256, 0, stream>>>(ws);
  k_enc_gi<<<TSEQ / 16, 256, 0, stream>>>(x, enc_emb, enc_wih, enc_bih, (float*)(ws + WS_GIENC));
  if (use_table)
    k_table<<<NV / 16, 256, 0, stream>>>(dec_emb, dec_wih, dec_bih, (float*)(ws + WS_TABLE));
  k_main<<<NBLK, NTHR, 0, stream>>>(enc_whh, enc_bhh, dec_emb, dec_wih, dec_whh, dec_bih,
                                    dec_bhh, w_out, b_out, out, ws, use_table);
}

// Round 4
// 16132.214 us; speedup vs baseline: 3.0267x; 2.7797x over previous
//
#include <hip/hip_runtime.h>
#include <stdint.h>

#define TSEQ 1024
#define H 256
#define H3 768
#define NV 50000
#define NBLK 256
#define NTHR 512
#define RPB 196            // 256 * 196 = 50176 >= 50000
#define SOS_TOK 2
#define SWEEP_LIMIT 150000

// ---- workspace layout (bytes) ----
#define WS_SALT   0                          // int, bumped by k_init every launch
#define WS_PART   4096                       // u64[2 slots][256 blocks][8 words] = 32 KB
#define WS_GIENC  65536                      // float[1024*768] = 3MB
#define WS_TABLE  (65536 + TSEQ * H3 * 4)
#define TABLE_BYTES ((size_t)NV * H3 * 4)

using u64 = unsigned long long;

// relaxed agent-scope atomics: write-through/bypass to LLC, NO wbl2/inv fences
__device__ __forceinline__ void awr(u64* p, u64 v) {
  __hip_atomic_store(p, v, __ATOMIC_RELAXED, __HIP_MEMORY_SCOPE_AGENT);
}
__device__ __forceinline__ u64 ard(u64* p) {
  return __hip_atomic_load(p, __ATOMIC_RELAXED, __HIP_MEMORY_SCOPE_AGENT);
}
__device__ __forceinline__ u64 pkf(unsigned tg, float f) {
  return ((u64)tg << 32) | (u64)__float_as_uint(f);
}
__device__ __forceinline__ u64 pki(unsigned tg, int v) {
  return ((u64)tg << 32) | (u64)(unsigned)v;
}
__device__ __forceinline__ float upf(u64 w) { return __uint_as_float((unsigned)w); }

// ---- init: bump per-launch salt (graph-replay safe, deterministic work) ----
extern "C" __global__ void k_init(char* ws) {
  if (threadIdx.x == 0) {
    unsigned* s = (unsigned*)(ws + WS_SALT);
    *s = *s + 1u;
  }
}

// ---- encoder input-transform: gi_enc[t][r] = b_ih[r] + w_ih[r,:] @ enc_emb[x[t]], 16 tokens/block ----
extern "C" __global__ void k_enc_gi(const int* __restrict__ x, const float* __restrict__ emb,
                                    const float* __restrict__ wih, const float* __restrict__ bih,
                                    float* __restrict__ gi) {
  int tid = threadIdx.x;
  int t0 = blockIdx.x * 16;
  __shared__ float4 se4[16][H / 4];
  float* se = (float*)se4;
  for (int idx = tid; idx < 16 * H; idx += 256) {
    int j = idx >> 8, k = idx & 255;
    se[j * H + k] = emb[(size_t)x[t0 + j] * H + k];
  }
  __syncthreads();
  for (int q = 0; q < 3; q++) {
    int r = q * H + tid;
    const float4* w4 = (const float4*)(wih + (size_t)r * H);
    float bb = bih[r];
    float a[16];
#pragma unroll
    for (int j = 0; j < 16; j++) a[j] = bb;
    for (int k = 0; k < H / 4; k++) {
      float4 wv = w4[k];
#pragma unroll
      for (int j = 0; j < 16; j++) {
        float4 ev = se4[j][k];
        a[j] += wv.x * ev.x + wv.y * ev.y + wv.z * ev.z + wv.w * ev.w;
      }
    }
#pragma unroll
    for (int j = 0; j < 16; j++) gi[(size_t)(t0 + j) * H3 + r] = a[j];
  }
}

// ---- decoder gi table: table[v][r] = b_ih[r] + w_ih[r,:] @ relu(dec_emb[v]) ----
extern "C" __global__ void k_table(const float* __restrict__ emb, const float* __restrict__ wih,
                                   const float* __restrict__ bih, float* __restrict__ table) {
  int tid = threadIdx.x;
  int v0 = blockIdx.x * 16;
  __shared__ float4 se4[16][H / 4];
  float* se = (float*)se4;
  for (int idx = tid; idx < 16 * H; idx += 256) {
    int j = idx >> 8, k = idx & 255;
    se[j * H + k] = fmaxf(emb[(size_t)(v0 + j) * H + k], 0.f);
  }
  __syncthreads();
  for (int q = 0; q < 3; q++) {
    int r = q * H + tid;
    const float4* w4 = (const float4*)(wih + (size_t)r * H);
    float bb = bih[r];
    float a[16];
#pragma unroll
    for (int j = 0; j < 16; j++) a[j] = bb;
    for (int k = 0; k < H / 4; k++) {
      float4 wv = w4[k];
#pragma unroll
      for (int j = 0; j < 16; j++) {
        float4 ev = se4[j][k];
        a[j] += wv.x * ev.x + wv.y * ev.y + wv.z * ev.z + wv.w * ev.w;
      }
    }
#pragma unroll
    for (int j = 0; j < 16; j++) table[(size_t)(v0 + j) * H3 + r] = a[j];
  }
}

// ---- persistent symmetric kernel: fence-free tagged-word exchange per step ----
extern "C" __global__ void __launch_bounds__(NTHR, 1)
k_main(const float* __restrict__ enc_whh, const float* __restrict__ enc_bhh,
       const float* __restrict__ dec_emb, const float* __restrict__ dec_wih,
       const float* __restrict__ dec_whh, const float* __restrict__ dec_bih,
       const float* __restrict__ dec_bhh, const float* __restrict__ w_out,
       const float* __restrict__ b_out, float* __restrict__ out,
       char* __restrict__ ws, int use_table) {
  const int b = blockIdx.x, tid = threadIdx.x;
  u64* part = (u64*)(ws + WS_PART);                 // [2][256][8]
  const float* gi_enc = (const float*)(ws + WS_GIENC);
  const float* table = (const float*)(ws + WS_TABLE);

  __shared__ float sh_h[H];
  __shared__ float sh_we[3][H];
  __shared__ float sh_wd[3][H];
  __shared__ float sh_wi[3][H];
  __shared__ float sh_gi[H3];
  __shared__ float gh_lds[H3];
  __shared__ float sh_logit[RPB];
  __shared__ float sh_bout[RPB];
  __shared__ float sh_gh3[3];
  __shared__ float sh_rv[8];     // row3 wave partials
  __shared__ float sh_mv[8];     // max-phase partials
  __shared__ int sh_mi[8];
  __shared__ float sh_sv[8];     // sum-phase partials
  __shared__ float sh_mv2[8];    // merge-max partials
  __shared__ int sh_mi2[8];
  __shared__ float sh_sv2[8];    // merge-sum partials
  __shared__ float sh_e[H];

  // ---- prologue staging ----
  for (int k = tid; k < 3 * H; k += NTHR) {
    int q = k >> 8, c = k & 255;
    sh_we[q][c] = enc_whh[(size_t)(3 * b + q) * H + c];
    sh_wd[q][c] = dec_whh[(size_t)(3 * b + q) * H + c];
    if (!use_table) sh_wi[q][c] = dec_wih[(size_t)(3 * b + q) * H + c];
  }
  const int rowbase = b * RPB;
  const int nrows = min(RPB, max(0, NV - rowbase));
  const int p = tid >> 1, hf = tid & 1;
  const bool wact = (p < nrows);
  float4 wreg[32];
  if (wact) {
    const float4* wp = (const float4*)(w_out + (size_t)(rowbase + p) * H + hf * 128);
#pragma unroll
    for (int i = 0; i < 32; ++i) wreg[i] = wp[i];
  } else {
#pragma unroll
    for (int i = 0; i < 32; ++i) wreg[i] = make_float4(0.f, 0.f, 0.f, 0.f);
  }
  if (tid < RPB) sh_bout[tid] = (tid < nrows) ? b_out[rowbase + tid] : 0.f;
  for (int j = tid; j < H; j += NTHR) sh_h[j] = 0.f;
  for (int j = tid; j < H3; j += NTHR) {
    gh_lds[j] = enc_bhh[j];   // w_hh @ 0 + b_hh
    sh_gi[j] = gi_enc[j];     // gi for t=0
  }
  const unsigned tagbase = (*(volatile unsigned*)(ws + WS_SALT)) * 4096u;
  __syncthreads();
  int e = 0;
  int tok = SOS_TOK;

  auto wave_maxidx = [&](float& mv, int& mi) {
#pragma unroll
    for (int off = 32; off >= 1; off >>= 1) {
      float ov = __shfl_xor(mv, off);
      int oi = __shfl_xor(mi, off);
      if (ov > mv || (ov == mv && oi < mi)) { mv = ov; mi = oi; }
    }
  };
  // rows 3b..3b+2 of (wr @ vin) + bias -> sh_gh3[0..2]
  auto row3 = [&](const float(&wr)[3][H], const float* bias, const float* vin) {
    int q = tid >> 7, i = tid & 127;
    float pp = 0.f;
    if (q < 3) pp = wr[q][2 * i] * vin[2 * i] + wr[q][2 * i + 1] * vin[2 * i + 1];
#pragma unroll
    for (int off = 32; off >= 1; off >>= 1) pp += __shfl_xor(pp, off);
    if (q < 3 && (tid & 63) == 0) sh_rv[tid >> 6] = pp;
    __syncthreads();
    if (tid < 3) sh_gh3[tid] = sh_rv[2 * tid] + sh_rv[2 * tid + 1] + bias[3 * b + tid];
    __syncthreads();
  };
  auto gru_step = [&]() {
    if (tid < H) {
      float gir = sh_gi[tid], giz = sh_gi[H + tid], gin = sh_gi[2 * H + tid];
      float ghr = gh_lds[tid], ghz = gh_lds[H + tid], ghn = gh_lds[2 * H + tid];
      float r = 1.f / (1.f + expf(-(gir + ghr)));
      float z = 1.f / (1.f + expf(-(giz + ghz)));
      float n = tanhf(gin + r * ghn);
      sh_h[tid] = (1.f - z) * n + z * sh_h[tid];
    }
    __syncthreads();
  };
  // publish 3 tagged words (gh rows) -- caller must be past a barrier covering sh_gh3
  auto pub3 = [&](unsigned tg) {
    if (tid == 0) {
      u64* d = part + (size_t)(tg & 1) * 2048 + (size_t)b * 8;
      awr(d + 0, pkf(tg, sh_gh3[0]));
      awr(d + 1, pkf(tg, sh_gh3[1]));
      awr(d + 2, pkf(tg, sh_gh3[2]));
    }
  };
  auto pub6 = [&](unsigned tg, float bmax, float bsum, int bidx) {
    if (tid == 0) {
      u64* d = part + (size_t)(tg & 1) * 2048 + (size_t)b * 8;
      awr(d + 0, pkf(tg, sh_gh3[0]));
      awr(d + 1, pkf(tg, sh_gh3[1]));
      awr(d + 2, pkf(tg, sh_gh3[2]));
      awr(d + 3, pkf(tg, bmax));
      awr(d + 4, pkf(tg, bsum));
      awr(d + 5, pki(tg, bidx));
    }
  };
  // poll until all 256 records carry tag tg; returns payloads for record[tid]
  auto poll3 = [&](unsigned tg, float& a0, float& a1, float& a2) -> bool {
    u64 w0 = 0, w1 = 0, w2 = 0;
    u64* base = part + (size_t)(tg & 1) * 2048 + (size_t)tid * 8;
    for (int sweep = 0;; ++sweep) {
      int ok = 1;
      if (tid < NBLK) {
        w0 = ard(base + 0); w1 = ard(base + 1); w2 = ard(base + 2);
        ok = ((unsigned)(w0 >> 32) == tg) & ((unsigned)(w1 >> 32) == tg) &
             ((unsigned)(w2 >> 32) == tg);
      }
      if (__syncthreads_and(ok)) break;
      if (sweep > SWEEP_LIMIT) return false;   // uniform across block
      __builtin_amdgcn_s_sleep(1);
    }
    a0 = upf(w0); a1 = upf(w1); a2 = upf(w2);
    return true;
  };
  auto poll6 = [&](unsigned tg, float& a0, float& a1, float& a2,
                   float& a3, float& a4, int& a5) -> bool {
    u64 w0 = 0, w1 = 0, w2 = 0, w3 = 0, w4 = 0, w5 = 0;
    u64* base = part + (size_t)(tg & 1) * 2048 + (size_t)tid * 8;
    for (int sweep = 0;; ++sweep) {
      int ok = 1;
      if (tid < NBLK) {
        w0 = ard(base + 0); w1 = ard(base + 1); w2 = ard(base + 2);
        w3 = ard(base + 3); w4 = ard(base + 4); w5 = ard(base + 5);
        ok = ((unsigned)(w0 >> 32) == tg) & ((unsigned)(w1 >> 32) == tg) &
             ((unsigned)(w2 >> 32) == tg) & ((unsigned)(w3 >> 32) == tg) &
             ((unsigned)(w4 >> 32) == tg) & ((unsigned)(w5 >> 32) == tg);
      }
      if (__syncthreads_and(ok)) break;
      if (sweep > SWEEP_LIMIT) return false;
      __builtin_amdgcn_s_sleep(1);
    }
    a0 = upf(w0); a1 = upf(w1); a2 = upf(w2); a3 = upf(w3); a4 = upf(w4);
    a5 = (int)(unsigned)w5;
    return true;
  };

  // ===================== ENCODER =====================
  for (int t = 0; t < TSEQ; ++t) {
    gru_step();                        // h_t from gi_enc[t], gh(h_{t-1})
    if (t + 1 < TSEQ) {
      row3(sh_we, enc_bhh, sh_h);      // gh rows for t+1
      ++e;
      unsigned tg = tagbase + (unsigned)e;
      pub3(tg);
      for (int j = tid; j < H3; j += NTHR)      // prefetch gi for t+1 during wait
        sh_gi[j] = gi_enc[(size_t)(t + 1) * H3 + j];
      float a0, a1, a2;
      if (!poll3(tg, a0, a1, a2)) return;
      if (tid < NBLK) { gh_lds[3 * tid] = a0; gh_lds[3 * tid + 1] = a1; gh_lds[3 * tid + 2] = a2; }
      __syncthreads();
    }
  }
  // ===================== BRIDGE: exchange dec-gh(h_enc) =====================
  {
    row3(sh_wd, dec_bhh, sh_h);
    ++e;
    unsigned tg = tagbase + (unsigned)e;
    pub3(tg);
    float a0, a1, a2;
    if (!poll3(tg, a0, a1, a2)) return;
    if (tid < NBLK) { gh_lds[3 * tid] = a0; gh_lds[3 * tid + 1] = a1; gh_lds[3 * tid + 2] = a2; }
    __syncthreads();
  }

  // ===================== DECODER =====================
  for (int t = 0; t < TSEQ; ++t) {
    // gi = b_ih + w_ih @ relu(emb[tok])
    if (use_table) {
      for (int j = tid; j < H3; j += NTHR) sh_gi[j] = table[(size_t)tok * H3 + j];
      __syncthreads();
    } else {
      for (int j = tid; j < H; j += NTHR) sh_e[j] = fmaxf(dec_emb[(size_t)tok * H + j], 0.f);
      __syncthreads();
      row3(sh_wi, dec_bih, sh_e);
      ++e;
      unsigned tg = tagbase + (unsigned)e;
      pub3(tg);
      float a0, a1, a2;
      if (!poll3(tg, a0, a1, a2)) return;
      if (tid < NBLK) { sh_gi[3 * tid] = a0; sh_gi[3 * tid + 1] = a1; sh_gi[3 * tid + 2] = a2; }
      __syncthreads();
    }
    gru_step();                        // h_t (bitwise-identical in all blocks)
    // logits from register-resident w_out
    float acc = 0.f;
    if (wact) {
      const float4* h4 = ((const float4*)sh_h) + hf * 32;
#pragma unroll
      for (int i = 0; i < 32; ++i) {
        float4 wv = wreg[i], hv = h4[i];
        acc += wv.x * hv.x + wv.y * hv.y + wv.z * hv.z + wv.w * hv.w;
      }
    }
    acc += __shfl_xor(acc, 1);
    if (wact && hf == 0) sh_logit[p] = acc + sh_bout[p];
    __syncthreads();
    // block-local max/argmax over own rows
    float mv = (tid < nrows) ? sh_logit[tid] : -INFINITY;
    int mi = (tid < nrows) ? (rowbase + tid) : 0x7fffffff;
    wave_maxidx(mv, mi);
    if ((tid & 63) == 0) { sh_mv[tid >> 6] = mv; sh_mi[tid >> 6] = mi; }
    __syncthreads();
    float bmax = sh_mv[0]; int bidx = sh_mi[0];
#pragma unroll
    for (int k = 1; k < 8; ++k)
      if (sh_mv[k] > bmax || (sh_mv[k] == bmax && sh_mi[k] < bidx)) { bmax = sh_mv[k]; bidx = sh_mi[k]; }
    // block-local sum of exp
    float ec = (tid < nrows) ? expf(sh_logit[tid] - bmax) : 0.f;
#pragma unroll
    for (int off = 32; off >= 1; off >>= 1) ec += __shfl_xor(ec, off);
    if ((tid & 63) == 0) sh_sv[tid >> 6] = ec;
    __syncthreads();
    float bsum = 0.f;
#pragma unroll
    for (int k = 0; k < 8; ++k) bsum += sh_sv[k];
    // gh rows for t+1
    row3(sh_wd, dec_bhh, sh_h);
    // one fence-free exchange: {gh3, bmax, bsum, bidx}
    ++e;
    unsigned tg = tagbase + (unsigned)e;
    pub6(tg, bmax, bsum, bidx);
    float a0, a1, a2, bm_e, sv; int ie;
    if (!poll6(tg, a0, a1, a2, bm_e, sv, ie)) return;
    if (tid < NBLK) { gh_lds[3 * tid] = a0; gh_lds[3 * tid + 1] = a1; gh_lds[3 * tid + 2] = a2; }
    if (tid >= NBLK) { bm_e = -INFINITY; sv = 0.f; ie = 0x7fffffff; }
    // redundant identical merge -> gmax, token, lse
    float mv2 = bm_e; int mi2 = ie;
    wave_maxidx(mv2, mi2);
    if ((tid & 63) == 0) { sh_mv2[tid >> 6] = mv2; sh_mi2[tid >> 6] = mi2; }
    __syncthreads();
    float gmax = sh_mv2[0]; int gidx = sh_mi2[0];
#pragma unroll
    for (int k = 1; k < 8; ++k)
      if (sh_mv2[k] > gmax || (sh_mv2[k] == gmax && sh_mi2[k] < gidx)) { gmax = sh_mv2[k]; gidx = sh_mi2[k]; }
    float c = (tid < NBLK) ? sv * expf(bm_e - gmax) : 0.f;
#pragma unroll
    for (int off = 32; off >= 1; off >>= 1) c += __shfl_xor(c, off);
    if ((tid & 63) == 0) sh_sv2[tid >> 6] = c;
    __syncthreads();
    float S = 0.f;
#pragma unroll
    for (int k = 0; k < 8; ++k) S += sh_sv2[k];
    float lse = gmax + logf(S);
    if (tid < nrows) out[(size_t)t * NV + rowbase + tid] = sh_logit[tid] - lse;
    tok = gidx;
  }
}

extern "C" void kernel_launch(void* const* d_in, const int* in_sizes, int n_in,
                              void* d_out, int out_size, void* d_ws, size_t ws_size,
                              hipStream_t stream) {
  (void)in_sizes; (void)n_in; (void)out_size;
  const int* x = (const int*)d_in[0];
  const float* enc_emb = (const float*)d_in[1];
  const float* enc_wih = (const float*)d_in[2];
  const float* enc_whh = (const float*)d_in[3];
  const float* enc_bih = (const float*)d_in[4];
  const float* enc_bhh = (const float*)d_in[5];
  const float* dec_emb = (const float*)d_in[6];
  const float* dec_wih = (const float*)d_in[7];
  const float* dec_whh = (const float*)d_in[8];
  const float* dec_bih = (const float*)d_in[9];
  const float* dec_bhh = (const float*)d_in[10];
  const float* w_out = (const float*)d_in[11];
  const float* b_out = (const float*)d_in[12];
  float* out = (float*)d_out;
  char* ws = (char*)d_ws;

  int use_table = (ws_size >= (size_t)WS_TABLE + TABLE_BYTES) ? 1 : 0;

  k_init<<<1, 64, 0, stream>>>(ws);
  k_enc_gi<<<TSEQ / 16, 256, 0, stream>>>(x, enc_emb, enc_wih, enc_bih, (float*)(ws + WS_GIENC));
  if (use_table)
    k_table<<<NV / 16, 256, 0, stream>>>(dec_emb, dec_wih, dec_bih, (float*)(ws + WS_TABLE));
  k_main<<<NBLK, NTHR, 0, stream>>>(enc_whh, enc_bhh, dec_emb, dec_wih, dec_whh, dec_bih,
                                    dec_bhh, w_out, b_out, out, ws, use_table);
}

// Round 5
// 12867.879 us; speedup vs baseline: 3.7945x; 1.2537x over previous
//
#include <hip/hip_runtime.h>
#include <stdint.h>

#define TSEQ 1024
#define H 256
#define H3 768
#define NV 50000
#define NBLK 256
#define NTHR 512
#define RPB 196            // 256 * 196 = 50176 >= 50000
#define SOS_TOK 2
#define SWEEP_LIMIT 150000
#define VAL_LIMIT 65536

// ---- workspace layout (bytes) ----
#define WS_SALT   0                          // u32, bumped by k_init every launch
#define WS_CNT    1024                       // u32[16] at 64B stride (2 parities x 8 lines)
#define WS_PART   4096                       // u64[2 slots][256 blocks][8 words] = 32 KB
#define WS_GIENC  65536                      // float[1024*768] = 3MB
#define WS_TABLE  (65536 + TSEQ * H3 * 4)
#define TABLE_BYTES ((size_t)NV * H3 * 4)

using u64 = unsigned long long;

// relaxed agent-scope atomics: straight to LLC, no wbl2/inv fences
__device__ __forceinline__ void awr(u64* p, u64 v) {
  __hip_atomic_store(p, v, __ATOMIC_RELAXED, __HIP_MEMORY_SCOPE_AGENT);
}
__device__ __forceinline__ u64 ard(u64* p) {
  return __hip_atomic_load(p, __ATOMIC_RELAXED, __HIP_MEMORY_SCOPE_AGENT);
}
__device__ __forceinline__ unsigned ard32(unsigned* p) {
  return __hip_atomic_load(p, __ATOMIC_RELAXED, __HIP_MEMORY_SCOPE_AGENT);
}
__device__ __forceinline__ u64 pkf(unsigned tg, float f) {
  return ((u64)tg << 32) | (u64)__float_as_uint(f);
}
__device__ __forceinline__ u64 pki(unsigned tg, int v) {
  return ((u64)tg << 32) | (u64)(unsigned)v;
}
__device__ __forceinline__ float upf(u64 w) { return __uint_as_float((unsigned)w); }

// ---- init: bump salt, reset arrival counters (runs stream-ordered before k_main) ----
extern "C" __global__ void k_init(char* ws) {
  int tid = threadIdx.x;
  if (tid == 0) {
    unsigned* s = (unsigned*)(ws + WS_SALT);
    *s = *s + 1u;
  }
  if (tid < 16) *(unsigned*)(ws + WS_CNT + tid * 64) = 0u;
}

// ---- encoder input-transform: gi_enc[t][r] = b_ih[r] + w_ih[r,:] @ enc_emb[x[t]], 16 tokens/block ----
extern "C" __global__ void k_enc_gi(const int* __restrict__ x, const float* __restrict__ emb,
                                    const float* __restrict__ wih, const float* __restrict__ bih,
                                    float* __restrict__ gi) {
  int tid = threadIdx.x;
  int t0 = blockIdx.x * 16;
  __shared__ float4 se4[16][H / 4];
  float* se = (float*)se4;
  for (int idx = tid; idx < 16 * H; idx += 256) {
    int j = idx >> 8, k = idx & 255;
    se[j * H + k] = emb[(size_t)x[t0 + j] * H + k];
  }
  __syncthreads();
  for (int q = 0; q < 3; q++) {
    int r = q * H + tid;
    const float4* w4 = (const float4*)(wih + (size_t)r * H);
    float bb = bih[r];
    float a[16];
#pragma unroll
    for (int j = 0; j < 16; j++) a[j] = bb;
    for (int k = 0; k < H / 4; k++) {
      float4 wv = w4[k];
#pragma unroll
      for (int j = 0; j < 16; j++) {
        float4 ev = se4[j][k];
        a[j] += wv.x * ev.x + wv.y * ev.y + wv.z * ev.z + wv.w * ev.w;
      }
    }
#pragma unroll
    for (int j = 0; j < 16; j++) gi[(size_t)(t0 + j) * H3 + r] = a[j];
  }
}

// ---- decoder gi table: table[v][r] = b_ih[r] + w_ih[r,:] @ relu(dec_emb[v]) ----
extern "C" __global__ void k_table(const float* __restrict__ emb, const float* __restrict__ wih,
                                   const float* __restrict__ bih, float* __restrict__ table) {
  int tid = threadIdx.x;
  int v0 = blockIdx.x * 16;
  __shared__ float4 se4[16][H / 4];
  float* se = (float*)se4;
  for (int idx = tid; idx < 16 * H; idx += 256) {
    int j = idx >> 8, k = idx & 255;
    se[j * H + k] = fmaxf(emb[(size_t)(v0 + j) * H + k], 0.f);
  }
  __syncthreads();
  for (int q = 0; q < 3; q++) {
    int r = q * H + tid;
    const float4* w4 = (const float4*)(wih + (size_t)r * H);
    float bb = bih[r];
    float a[16];
#pragma unroll
    for (int j = 0; j < 16; j++) a[j] = bb;
    for (int k = 0; k < H / 4; k++) {
      float4 wv = w4[k];
#pragma unroll
      for (int j = 0; j < 16; j++) {
        float4 ev = se4[j][k];
        a[j] += wv.x * ev.x + wv.y * ev.y + wv.z * ev.z + wv.w * ev.w;
      }
    }
#pragma unroll
    for (int j = 0; j < 16; j++) table[(size_t)(v0 + j) * H3 + r] = a[j];
  }
}

// ---- persistent symmetric kernel: counter-notified tagged-record exchange ----
extern "C" __global__ void __launch_bounds__(NTHR, 1)
k_main(const float* __restrict__ enc_whh, const float* __restrict__ enc_bhh,
       const float* __restrict__ dec_emb, const float* __restrict__ dec_wih,
       const float* __restrict__ dec_whh, const float* __restrict__ dec_bih,
       const float* __restrict__ dec_bhh, const float* __restrict__ w_out,
       const float* __restrict__ b_out, float* __restrict__ out,
       char* __restrict__ ws, int use_table) {
  const int b = blockIdx.x, tid = threadIdx.x;
  u64* part = (u64*)(ws + WS_PART);                 // [2][256][8] u64, 64B/record
  unsigned* cnt = (unsigned*)(ws + WS_CNT);         // stride 16 u32 (64B lines)
  const float* gi_enc = (const float*)(ws + WS_GIENC);
  const float* table = (const float*)(ws + WS_TABLE);

  __shared__ float sh_h[H];
  __shared__ float sh_we[3][H];
  __shared__ float sh_wd[3][H];
  __shared__ float sh_wi[3][H];
  __shared__ float sh_gi[H3];
  __shared__ float gh_lds[H3];
  __shared__ float sh_logit[RPB];
  __shared__ float sh_bout[RPB];
  __shared__ float sh_gh3[3];
  __shared__ float sh_rv[8];
  __shared__ float sh_mv[8];
  __shared__ int sh_mi[8];
  __shared__ float sh_sv[8];
  __shared__ float sh_mv2[8];
  __shared__ int sh_mi2[8];
  __shared__ float sh_sv2[8];
  __shared__ float sh_e[H];

  // ---- prologue staging ----
  for (int k = tid; k < 3 * H; k += NTHR) {
    int q = k >> 8, c = k & 255;
    sh_we[q][c] = enc_whh[(size_t)(3 * b + q) * H + c];
    sh_wd[q][c] = dec_whh[(size_t)(3 * b + q) * H + c];
    if (!use_table) sh_wi[q][c] = dec_wih[(size_t)(3 * b + q) * H + c];
  }
  const int rowbase = b * RPB;
  const int nrows = min(RPB, max(0, NV - rowbase));
  const int p = tid >> 1, hf = tid & 1;
  const bool wact = (p < nrows);
  float4 wreg[32];
  if (wact) {
    const float4* wp = (const float4*)(w_out + (size_t)(rowbase + p) * H + hf * 128);
#pragma unroll
    for (int i = 0; i < 32; ++i) wreg[i] = wp[i];
  } else {
#pragma unroll
    for (int i = 0; i < 32; ++i) wreg[i] = make_float4(0.f, 0.f, 0.f, 0.f);
  }
  if (tid < RPB) sh_bout[tid] = (tid < nrows) ? b_out[rowbase + tid] : 0.f;
  for (int j = tid; j < H; j += NTHR) sh_h[j] = 0.f;
  for (int j = tid; j < H3; j += NTHR) {
    gh_lds[j] = enc_bhh[j];   // w_hh @ 0 + b_hh
    sh_gi[j] = gi_enc[j];     // gi for t=0
  }
  const unsigned tagbase = (*(volatile unsigned*)(ws + WS_SALT)) * 65536u;
  __syncthreads();
  int e = 0;
  int tok = SOS_TOK;

  auto wave_maxidx = [&](float& mv, int& mi) {
#pragma unroll
    for (int off = 32; off >= 1; off >>= 1) {
      float ov = __shfl_xor(mv, off);
      int oi = __shfl_xor(mi, off);
      if (ov > mv || (ov == mv && oi < mi)) { mv = ov; mi = oi; }
    }
  };
  // rows 3b..3b+2 of (wr @ vin) + bias -> sh_gh3[0..2]
  auto row3 = [&](const float(&wr)[3][H], const float* bias, const float* vin) {
    int q = tid >> 7, i = tid & 127;
    float pp = 0.f;
    if (q < 3) pp = wr[q][2 * i] * vin[2 * i] + wr[q][2 * i + 1] * vin[2 * i + 1];
#pragma unroll
    for (int off = 32; off >= 1; off >>= 1) pp += __shfl_xor(pp, off);
    if (q < 3 && (tid & 63) == 0) sh_rv[tid >> 6] = pp;
    __syncthreads();
    if (tid < 3) sh_gh3[tid] = sh_rv[2 * tid] + sh_rv[2 * tid + 1] + bias[3 * b + tid];
    __syncthreads();
  };
  auto gru_step = [&]() {
    if (tid < H) {
      float gir = sh_gi[tid], giz = sh_gi[H + tid], gin = sh_gi[2 * H + tid];
      float ghr = gh_lds[tid], ghz = gh_lds[H + tid], ghn = gh_lds[2 * H + tid];
      float r = 1.f / (1.f + expf(-(gir + ghr)));
      float z = 1.f / (1.f + expf(-(giz + ghz)));
      float n = tanhf(gin + r * ghn);
      sh_h[tid] = (1.f - z) * n + z * sh_h[tid];
    }
    __syncthreads();
  };
  // wait until all 256 blocks have announced epoch est (8 counter lines only)
  auto wait_cnt = [&](int est) -> bool {
    unsigned par = (unsigned)est & 1u;
    unsigned uses = (unsigned)((par ? est + 1 : est) >> 1);
    unsigned tgt = 32u * uses;
    for (int sweep = 0;; ++sweep) {
      int ok = 1;
      if (tid < 8) ok = (ard32(cnt + (par * 8 + tid) * 16) >= tgt);
      if (__syncthreads_and(ok)) return true;
      if (sweep > SWEEP_LIMIT) return false;
      __builtin_amdgcn_s_sleep(1);
    }
  };
  auto announce = [&](unsigned tg) {
    __hip_atomic_fetch_add(cnt + ((tg & 1) * 8 + (b & 7)) * 16, 1u,
                           __ATOMIC_RELAXED, __HIP_MEMORY_SCOPE_AGENT);
  };
  // record words: w0={tag,bmax} w1={tag,idx} w2..w4={tag,gh0..2} w5={tag,bsum}
  auto pub3 = [&](unsigned tg) {
    if (tid == 0) {
      u64* d = part + (size_t)(tg & 1) * 2048 + (size_t)b * 8;
      awr(d + 2, pkf(tg, sh_gh3[0]));
      awr(d + 3, pkf(tg, sh_gh3[1]));
      awr(d + 4, pkf(tg, sh_gh3[2]));
      announce(tg);
    }
  };
  auto pub6 = [&](unsigned tg, float bmax, float bsum, int bidx) {
    if (tid == 0) {
      u64* d = part + (size_t)(tg & 1) * 2048 + (size_t)b * 8;
      awr(d + 0, pkf(tg, bmax));
      awr(d + 1, pki(tg, bidx));
      awr(d + 2, pkf(tg, sh_gh3[0]));
      awr(d + 3, pkf(tg, sh_gh3[1]));
      awr(d + 4, pkf(tg, sh_gh3[2]));
      awr(d + 5, pkf(tg, bsum));
      announce(tg);
    }
  };
  // gather w2..w4 with tag validation (re-read micro-loop, usually 1 pass)
  auto gather3 = [&](unsigned tg, u64& w2, u64& w3, u64& w4) -> bool {
    u64* base = part + (size_t)(tg & 1) * 2048 + (size_t)tid * 8;
    int valid = (tid >= NBLK);
    for (int tries = 0;; ++tries) {
      if (tid < NBLK && !valid) {
        w2 = ard(base + 2); w3 = ard(base + 3); w4 = ard(base + 4);
        valid = ((unsigned)(w2 >> 32) == tg) & ((unsigned)(w3 >> 32) == tg) &
                ((unsigned)(w4 >> 32) == tg);
      }
      if (__syncthreads_and(valid)) return true;
      if (tries > VAL_LIMIT) return false;
      __builtin_amdgcn_s_sleep(1);
    }
  };
  auto gather6 = [&](unsigned tg, u64& w0, u64& w1, u64& w2, u64& w3, u64& w4, u64& w5) -> bool {
    u64* base = part + (size_t)(tg & 1) * 2048 + (size_t)tid * 8;
    int valid = (tid >= NBLK);
    for (int tries = 0;; ++tries) {
      if (tid < NBLK && !valid) {
        w0 = ard(base + 0); w1 = ard(base + 1); w2 = ard(base + 2);
        w3 = ard(base + 3); w4 = ard(base + 4); w5 = ard(base + 5);
        valid = ((unsigned)(w0 >> 32) == tg) & ((unsigned)(w1 >> 32) == tg) &
                ((unsigned)(w2 >> 32) == tg) & ((unsigned)(w3 >> 32) == tg) &
                ((unsigned)(w4 >> 32) == tg) & ((unsigned)(w5 >> 32) == tg);
      }
      if (__syncthreads_and(valid)) return true;
      if (tries > VAL_LIMIT) return false;
      __builtin_amdgcn_s_sleep(1);
    }
  };

  // ===================== ENCODER =====================
  for (int t = 0; t < TSEQ; ++t) {
    gru_step();                        // h_t from gi_enc[t], gh(h_{t-1})
    if (t + 1 < TSEQ) {
      row3(sh_we, enc_bhh, sh_h);      // gh rows for t+1
      ++e;
      unsigned tg = tagbase + (unsigned)e;
      pub3(tg);
      for (int j = tid; j < H3; j += NTHR)      // prefetch gi for t+1 during wait
        sh_gi[j] = gi_enc[(size_t)(t + 1) * H3 + j];
      if (!wait_cnt(e)) return;
      u64 w2, w3, w4;
      if (!gather3(tg, w2, w3, w4)) return;
      if (tid < NBLK) {
        gh_lds[3 * tid] = upf(w2); gh_lds[3 * tid + 1] = upf(w3); gh_lds[3 * tid + 2] = upf(w4);
      }
      __syncthreads();
    }
  }
  // ===================== BRIDGE: exchange dec-gh(h_enc) =====================
  {
    row3(sh_wd, dec_bhh, sh_h);
    ++e;
    unsigned tg = tagbase + (unsigned)e;
    pub3(tg);
    if (!wait_cnt(e)) return;
    u64 w2, w3, w4;
    if (!gather3(tg, w2, w3, w4)) return;
    if (tid < NBLK) {
      gh_lds[3 * tid] = upf(w2); gh_lds[3 * tid + 1] = upf(w3); gh_lds[3 * tid + 2] = upf(w4);
    }
    __syncthreads();
  }

  // ===================== DECODER =====================
  // iteration layout: [gather prev exchange -> tok, gi prefetch, lse, out row t-1 handled inline]
  for (int t = 0; t < TSEQ; ++t) {
    // --- gi for current token ---
    if (use_table) {
      float2 gp = make_float2(0.f, 0.f);
      if (tid < 384) gp = *(const float2*)(table + (size_t)tok * H3 + 2 * tid);
      if (tid < 384) { sh_gi[2 * tid] = gp.x; sh_gi[2 * tid + 1] = gp.y; }
      __syncthreads();
    } else {
      for (int j = tid; j < H; j += NTHR) sh_e[j] = fmaxf(dec_emb[(size_t)tok * H + j], 0.f);
      __syncthreads();
      row3(sh_wi, dec_bih, sh_e);
      ++e;
      unsigned tg = tagbase + (unsigned)e;
      pub3(tg);
      if (!wait_cnt(e)) return;
      u64 w2, w3, w4;
      if (!gather3(tg, w2, w3, w4)) return;
      if (tid < NBLK) {
        sh_gi[3 * tid] = upf(w2); sh_gi[3 * tid + 1] = upf(w3); sh_gi[3 * tid + 2] = upf(w4);
      }
      __syncthreads();
    }
    gru_step();                        // h_t (bitwise-identical in all blocks)
    // logits from register-resident w_out
    float acc = 0.f;
    if (wact) {
      const float4* h4 = ((const float4*)sh_h) + hf * 32;
#pragma unroll
      for (int i = 0; i < 32; ++i) {
        float4 wv = wreg[i], hv = h4[i];
        acc += wv.x * hv.x + wv.y * hv.y + wv.z * hv.z + wv.w * hv.w;
      }
    }
    acc += __shfl_xor(acc, 1);
    if (wact && hf == 0) sh_logit[p] = acc + sh_bout[p];
    __syncthreads();
    // block-local max/argmax
    float mv = (tid < nrows) ? sh_logit[tid] : -INFINITY;
    int mi = (tid < nrows) ? (rowbase + tid) : 0x7fffffff;
    wave_maxidx(mv, mi);
    if ((tid & 63) == 0) { sh_mv[tid >> 6] = mv; sh_mi[tid >> 6] = mi; }
    __syncthreads();
    float bmax = sh_mv[0]; int bidx = sh_mi[0];
#pragma unroll
    for (int k = 1; k < 8; ++k)
      if (sh_mv[k] > bmax || (sh_mv[k] == bmax && sh_mi[k] < bidx)) { bmax = sh_mv[k]; bidx = sh_mi[k]; }
    // block-local sum of exp (output-only path: fast exp ok)
    float ec = (tid < nrows) ? __expf(sh_logit[tid] - bmax) : 0.f;
#pragma unroll
    for (int off = 32; off >= 1; off >>= 1) ec += __shfl_xor(ec, off);
    if ((tid & 63) == 0) sh_sv[tid >> 6] = ec;
    __syncthreads();
    float bsum = 0.f;
#pragma unroll
    for (int k = 0; k < 8; ++k) bsum += sh_sv[k];
    // gh rows for t+1
    row3(sh_wd, dec_bhh, sh_h);
    // one exchange: {bmax, idx, gh0..2, bsum}
    ++e;
    unsigned tg = tagbase + (unsigned)e;
    pub6(tg, bmax, bsum, bidx);
    if (!wait_cnt(e)) return;
    u64 w0, w1, w2, w3, w4, w5;
    if (!gather6(tg, w0, w1, w2, w3, w4, w5)) return;
    // merge argmax FIRST -> tok (so the gi table load can issue ASAP)
    float mv2 = (tid < NBLK) ? upf(w0) : -INFINITY;
    int mi2 = (tid < NBLK) ? (int)(unsigned)w1 : 0x7fffffff;
    wave_maxidx(mv2, mi2);
    if ((tid & 63) == 0) { sh_mv2[tid >> 6] = mv2; sh_mi2[tid >> 6] = mi2; }
    __syncthreads();
    float gmax = sh_mv2[0]; int gidx = sh_mi2[0];
#pragma unroll
    for (int k = 1; k < 8; ++k)
      if (sh_mv2[k] > gmax || (sh_mv2[k] == gmax && sh_mi2[k] < gidx)) { gmax = sh_mv2[k]; gidx = sh_mi2[k]; }
    tok = gidx;
    // scatter gh + merge lse while (next iteration's) table loads can be prefetched by HW
    if (tid < NBLK) {
      gh_lds[3 * tid] = upf(w2); gh_lds[3 * tid + 1] = upf(w3); gh_lds[3 * tid + 2] = upf(w4);
    }
    float c = (tid < NBLK) ? upf(w5) * __expf(upf(w0) - gmax) : 0.f;
#pragma unroll
    for (int off = 32; off >= 1; off >>= 1) c += __shfl_xor(c, off);
    if ((tid & 63) == 0) sh_sv2[tid >> 6] = c;
    __syncthreads();
    float S = 0.f;
#pragma unroll
    for (int k = 0; k < 8; ++k) S += sh_sv2[k];
    float lse = gmax + logf(S);
    if (tid < nrows) out[(size_t)t * NV + rowbase + tid] = sh_logit[tid] - lse;
    // gh_lds writes are barrier-covered by the gru_step/sh_gi barriers next iteration
  }
}

extern "C" void kernel_launch(void* const* d_in, const int* in_sizes, int n_in,
                              void* d_out, int out_size, void* d_ws, size_t ws_size,
                              hipStream_t stream) {
  (void)in_sizes; (void)n_in; (void)out_size;
  const int* x = (const int*)d_in[0];
  const float* enc_emb = (const float*)d_in[1];
  const float* enc_wih = (const float*)d_in[2];
  const float* enc_whh = (const float*)d_in[3];
  const float* enc_bih = (const float*)d_in[4];
  const float* enc_bhh = (const float*)d_in[5];
  const float* dec_emb = (const float*)d_in[6];
  const float* dec_wih = (const float*)d_in[7];
  const float* dec_whh = (const float*)d_in[8];
  const float* dec_bih = (const float*)d_in[9];
  const float* dec_bhh = (const float*)d_in[10];
  const float* w_out = (const float*)d_in[11];
  const float* b_out = (const float*)d_in[12];
  float* out = (float*)d_out;
  char* ws = (char*)d_ws;

  int use_table = (ws_size >= (size_t)WS_TABLE + TABLE_BYTES) ? 1 : 0;

  k_init<<<1, 64, 0, stream>>>(ws);
  k_enc_gi<<<TSEQ / 16, 256, 0, stream>>>(x, enc_emb, enc_wih, enc_bih, (float*)(ws + WS_GIENC));
  if (use_table)
    k_table<<<NV / 16, 256, 0, stream>>>(dec_emb, dec_wih, dec_bih, (float*)(ws + WS_TABLE));
  k_main<<<NBLK, NTHR, 0, stream>>>(enc_whh, enc_bhh, dec_emb, dec_wih, dec_whh, dec_bih,
                                    dec_bhh, w_out, b_out, out, ws, use_table);
}